// Round 8
// baseline (115.151 us; speedup 1.0000x reference)
//
#include <hip/hip_runtime.h>
#include <hip/hip_bf16.h>

// B=64, M=16, T=2048, L=64, K=32, N=1985
#define B_ 64
#define M_ 16
#define T_ 2048
#define L_ 64
#define K_ 32
#define N_ (T_ - L_ + 1)   // 1985
#define KMN (K_ * M_ * N_) // 1,016,320 (= 4 * 254,080 exactly)
#define TN 64              // n-positions per block
#define NTH 256            // 4 waves: wave w owns n-subtile [16w,16w+16), both k-tiles
#define XROW 128           // xbuf row elems (127 used, padded)
#define STSTR 72           // st row stride elems (64+8)
#define SQSTR 68           // sqw row stride (64+4)

typedef __attribute__((ext_vector_type(8))) short bf16x8;
typedef __attribute__((ext_vector_type(4))) float f32x4;

__device__ __forceinline__ unsigned short f2bf(float f) {
    __hip_bfloat16 h = __float2bfloat16(f);
    return __builtin_bit_cast(unsigned short, h);
}

// funnel: low 32 of ((hi:lo) >> sh), sh in {0,16} -> v_alignbit_b32
__device__ __forceinline__ unsigned funnel16(unsigned lo, unsigned hi, unsigned sh) {
    return (unsigned)(((((unsigned long long)hi) << 32) | lo) >> sh);
}

// Extract 16B at byte offset 2*rho from the 32B window {a,b} (aligned b128 pair).
__device__ __forceinline__ bf16x8 extract_frag(uint4 a, uint4 b, unsigned sh, int c2) {
    unsigned t0 = funnel16(a.x, a.y, sh), t1 = funnel16(a.y, a.z, sh);
    unsigned t2 = funnel16(a.z, a.w, sh), t3 = funnel16(a.w, b.x, sh);
    unsigned t4 = funnel16(b.x, b.y, sh), t5 = funnel16(b.y, b.z, sh);
    unsigned t6 = funnel16(b.z, b.w, sh);
    const bool s2 = (c2 & 2), s1 = (c2 & 1);
    unsigned u0 = s2 ? t2 : t0, u1 = s2 ? t3 : t1, u2 = s2 ? t4 : t2;
    unsigned u3 = s2 ? t5 : t3, u4 = s2 ? t6 : t4;
    union { unsigned u[4]; bf16x8 v; } cvt;
    cvt.u[0] = s1 ? u1 : u0; cvt.u[1] = s1 ? u2 : u1;
    cvt.u[2] = s1 ? u3 : u2; cvt.u[3] = s1 ? u4 : u3;
    return cvt.v;
}

// pen[i] = elu(-pmap[i]) + 2 (flat over K*M*N); ss[k] = sum_l shp[k][l]^2 (fp32);
// out[] initialized to +inf. All fused in one small kernel.
__global__ void pen_init_kernel(const float* __restrict__ pmap,
                                const float* __restrict__ shp,
                                float* __restrict__ pen,
                                float* __restrict__ ss_ws,
                                unsigned* __restrict__ out) {
    const int gid = blockIdx.x * 256 + threadIdx.x;
    if (gid < B_ * K_) out[gid] = 0x7F800000u;  // +inf
    if (gid < K_) {
        float s = 0.f;
        for (int l = 0; l < L_; ++l) { float v = shp[gid * L_ + l]; s = fmaf(v, v, s); }
        ss_ws[gid] = s;
    }
    if (gid < KMN / 4) {
        const int i4 = gid * 4;
        float4 p = *(const float4*)(pmap + i4);
        float4 r;
        r.x = (p.x < 0.f) ? (2.f - p.x) : (__expf(-p.x) + 1.f);
        r.y = (p.y < 0.f) ? (2.f - p.y) : (__expf(-p.y) + 1.f);
        r.z = (p.z < 0.f) ? (2.f - p.z) : (__expf(-p.z) + 1.f);
        r.w = (p.w < 0.f) ? (2.f - p.w) : (__expf(-p.w) + 1.f);
        *(float4*)(pen + i4) = r;
    }
}

__global__ __launch_bounds__(NTH, 2)
void shapelet_mfma_kernel(const float* __restrict__ x,
                          const float* __restrict__ shp,
                          const float* __restrict__ pen,
                          const float* __restrict__ ss_ws,
                          unsigned* __restrict__ out) {
    // LDS: 4096 + 4608 + 4352 + 512 = 13.6 KB -> 8 blocks/CU (wave-capped)
    __shared__ __align__(16) unsigned short xbuf[M_][XROW];  // x as bf16 bits
    __shared__ __align__(16) unsigned short st[K_][STSTR];   // shapelets [k][l] bf16
    __shared__ __align__(16) float sqw[M_][SQSTR];           // fp32 sliding sum x^2
    __shared__ float red[4][2][16];                          // per-wave min staging

    const int tid = threadIdx.x;
    const int n0 = blockIdx.x * TN;
    const int b  = blockIdx.y;
    const bool fast = (n0 + TN < T_);   // false only for last tile (n0=1984)

    // ---- per-lane MFMA coordinates (needed early for pen prefetch) ----
    const int lane = tid & 63;
    const int w  = tid >> 6;       // wave -> n-subtile [16w, 16w+16)
    const int rl = lane & 15;      // A-row (n within subtile) / B-col (k within tile)
    const int q  = lane >> 4;      // quad
    const int rho = rl & 7, r8 = rl >> 3;
    const unsigned sh = (unsigned)((rho & 1) * 16);
    const int c2 = rho >> 1;
    const int Gb = 2 * w + q + r8; // aligned 16B-group base for A windows
    const int nrow = n0 + 16 * w + 4 * q;   // lane's 4 output rows: nrow + reg

    const float* pb0 = pen + (size_t)rl * (M_ * N_) + nrow;         // k = rl
    const float* pb1 = pb0 + (size_t)16 * M_ * N_;                  // k = rl+16

#define PEN_LOAD(mi, P0, P1) do {                                              \
        if (fast) {                                                            \
            P0 = *(const float4*)(pb0 + (size_t)(mi) * N_);                    \
            P1 = *(const float4*)(pb1 + (size_t)(mi) * N_);                    \
        } else {                                                               \
            P0 = make_float4(2.f, 2.f, 2.f, 2.f);                              \
            P1 = make_float4(2.f, 2.f, 2.f, 2.f);                              \
            const float* r0_ = pb0 + (size_t)(mi) * N_;                        \
            const float* r1_ = pb1 + (size_t)(mi) * N_;                        \
            if (nrow     < N_) { P0.x = r0_[0]; P1.x = r1_[0]; }               \
            if (nrow + 1 < N_) { P0.y = r0_[1]; P1.y = r1_[1]; }               \
            if (nrow + 2 < N_) { P0.z = r0_[2]; P1.z = r1_[2]; }               \
            if (nrow + 3 < N_) { P0.w = r0_[3]; P1.w = r1_[3]; }               \
        }                                                                      \
    } while (0)

    // ---- prefetch pen for m=0..3 and ss (complete during staging) ----
    float4 pf0[4], pf1[4];
    PEN_LOAD(0, pf0[0], pf1[0]);
    PEN_LOAD(1, pf0[1], pf1[1]);
    PEN_LOAD(2, pf0[2], pf1[2]);
    PEN_LOAD(3, pf0[3], pf1[3]);
    const float ssk0 = ss_ws[rl], ssk1 = ss_ws[16 + rl];

    // ---- stage x[b][m][n0..n0+127] as bf16 (fast: float4; slow: guarded) ----
    const float* xb = x + ((size_t)b * M_) * T_ + n0;
    for (int g = tid; g < M_ * 32; g += NTH) {
        const int m = g >> 5, j4 = (g & 31) * 4;
        const float* src = xb + m * T_ + j4;
        float4 v;
        if (fast) {
            v = *(const float4*)src;
        } else {
            v = make_float4(0.f, 0.f, 0.f, 0.f);
            const int t = n0 + j4;
            if (t     < T_) v.x = src[0];
            if (t + 1 < T_) v.y = src[1];
            if (t + 2 < T_) v.z = src[2];
            if (t + 3 < T_) v.w = src[3];
        }
        ushort4 sv = { f2bf(v.x), f2bf(v.y), f2bf(v.z), f2bf(v.w) };
        *(ushort4*)&xbuf[m][j4] = sv;
    }
    // ---- stage shapelets st[k][l] bf16 ----
    for (int i = tid; i < K_ * 16; i += NTH) {
        const int k = i >> 4, l4 = (i & 15) * 4;
        float4 v = *(const float4*)(shp + k * L_ + l4);
        ushort4 sv = { f2bf(v.x), f2bf(v.y), f2bf(v.z), f2bf(v.w) };
        *(ushort4*)&st[k][l4] = sv;
    }
    // ---- sqw fp32 sliding window: 8 threads per m, 8 n each (threads 0..127) ----
    if (tid < M_ * 8) {
        const int m = tid >> 3, j0 = (tid & 7) * 8;
        const float* xr = x + ((size_t)b * M_ + m) * T_ + n0;
        float s = 0.f;
        if (fast) {
#pragma unroll
            for (int qd = 0; qd < 16; ++qd) {
                float4 v = *(const float4*)(xr + j0 + qd * 4);
                s = fmaf(v.x, v.x, s); s = fmaf(v.y, v.y, s);
                s = fmaf(v.z, v.z, s); s = fmaf(v.w, v.w, s);
            }
            sqw[m][j0] = s;
#pragma unroll
            for (int d = 1; d < 8; ++d) {
                float a = xr[j0 + d + L_ - 1], r = xr[j0 + d - 1];
                s += a * a - r * r;
                sqw[m][j0 + d] = s;
            }
        } else {
            for (int l = 0; l < L_; ++l) {
                float v = (n0 + j0 + l < T_) ? xr[j0 + l] : 0.f;
                s = fmaf(v, v, s);
            }
            sqw[m][j0] = s;
            for (int d = 1; d < 8; ++d) {
                float a = (n0 + j0 + d + L_ - 1 < T_) ? xr[j0 + d + L_ - 1] : 0.f;
                float r = (n0 + j0 + d - 1 < T_) ? xr[j0 + d - 1] : 0.f;
                s += a * a - r * r;
                sqw[m][j0 + d] = s;
            }
        }
    }
    __syncthreads();

    // b_frags (registers, whole kernel): st[16t+rl][8q+32h .. +7]
    bf16x8 bfr[2][2];
#pragma unroll
    for (int t = 0; t < 2; ++t)
#pragma unroll
        for (int h = 0; h < 2; ++h)
            bfr[t][h] = *(const bf16x8*)&st[16 * t + rl][8 * q + 32 * h];

    f32x4 wd0 = (f32x4)0.f, wd1 = (f32x4)0.f;
    const f32x4 zero = (f32x4)0.f;

#define COMPUTE_M(mi, P0, P1) do {                                             \
        const uint4* px = (const uint4*)&xbuf[mi][0];                          \
        uint4 w0_ = px[Gb],     w1_ = px[Gb + 1];                              \
        uint4 w2_ = px[Gb + 4], w3_ = px[Gb + 5];                              \
        bf16x8 A0 = extract_frag(w0_, w1_, sh, c2);                            \
        bf16x8 A1 = extract_frag(w2_, w3_, sh, c2);                            \
        f32x4 c0_ = __builtin_amdgcn_mfma_f32_16x16x32_bf16(A0, bfr[0][0], zero, 0, 0, 0); \
        c0_       = __builtin_amdgcn_mfma_f32_16x16x32_bf16(A1, bfr[0][1], c0_, 0, 0, 0);  \
        f32x4 c1_ = __builtin_amdgcn_mfma_f32_16x16x32_bf16(A0, bfr[1][0], zero, 0, 0, 0); \
        c1_       = __builtin_amdgcn_mfma_f32_16x16x32_bf16(A1, bfr[1][1], c1_, 0, 0, 0);  \
        f32x4 sq_ = *(const f32x4*)&sqw[mi][16 * w + 4 * q];                   \
        const float pe0_[4] = { P0.x, P0.y, P0.z, P0.w };                      \
        const float pe1_[4] = { P1.x, P1.y, P1.z, P1.w };                      \
        _Pragma("unroll")                                                      \
        for (int r = 0; r < 4; ++r) {                                          \
            float t0v = fmaf(-2.f, c0_[r], sq_[r] + ssk0);                     \
            wd0[r] = fmaf(pe0_[r], t0v, wd0[r]);                               \
            float t1v = fmaf(-2.f, c1_[r], sq_[r] + ssk1);                     \
            wd1[r] = fmaf(pe1_[r], t1v, wd1[r]);                               \
        }                                                                      \
    } while (0)

    // ---- main loop: use (m, m+1), prefetch (m+4, m+5) -> distance ~2 iters ----
#pragma unroll 1
    for (int mm = 0; mm < M_; mm += 2) {
        float4 q00 = pf0[0], q01 = pf1[0];
        float4 q10 = pf0[1], q11 = pf1[1];
        pf0[0] = pf0[2]; pf1[0] = pf1[2];
        pf0[1] = pf0[3]; pf1[1] = pf1[3];
        if (mm + 5 < M_) {
            PEN_LOAD(mm + 4, pf0[2], pf1[2]);
            PEN_LOAD(mm + 5, pf0[3], pf1[3]);
        }
        COMPUTE_M(mm,     q00, q01);
        COMPUTE_M(mm + 1, q10, q11);
    }

    // ---- min over lane's 4 rows -> across quads -> per-wave LDS stage ----
#pragma unroll
    for (int t = 0; t < 2; ++t) {
        float lmin = __int_as_float(0x7F800000);
        const f32x4& wdv = t ? wd1 : wd0;
#pragma unroll
        for (int r = 0; r < 4; ++r) {
            if (nrow + r < N_) lmin = fminf(lmin, wdv[r]);
        }
        lmin = fminf(lmin, __shfl_xor(lmin, 16));
        lmin = fminf(lmin, __shfl_xor(lmin, 32));
        if (q == 0) red[w][t][rl] = lmin;
    }
    __syncthreads();
    // ---- block reduce across 4 waves -> one atomic per (b,k): 32 per block ----
    if (tid < K_) {
        const int t = tid >> 4, kr = tid & 15;
        float v = fminf(fminf(red[0][t][kr], red[1][t][kr]),
                        fminf(red[2][t][kr], red[3][t][kr]));
        atomicMin(out + (size_t)b * K_ + tid, __float_as_uint(fmaxf(v, 0.f)));
    }
#undef PEN_LOAD
#undef COMPUTE_M
}

extern "C" void kernel_launch(void* const* d_in, const int* in_sizes, int n_in,
                              void* d_out, int out_size, void* d_ws, size_t ws_size,
                              hipStream_t stream) {
    const float* x    = (const float*)d_in[0];   // (B, M, T)
    const float* shp  = (const float*)d_in[1];   // (K, L)
    const float* pmap = (const float*)d_in[2];   // (K, M, N)
    unsigned* out = (unsigned*)d_out;            // (B, K) float bits
    float* pen   = (float*)d_ws;                 // (K, M, N) elu(-pmap)+2, 3.9 MB
    float* ss_ws = pen + KMN;                    // (K,) fp32 sum s^2

    pen_init_kernel<<<dim3((KMN / 4 + 255) / 256), dim3(256), 0, stream>>>(
        pmap, shp, pen, ss_ws, out);

    dim3 grid((N_ + TN - 1) / TN, B_);           // 32 x 64 = 2048 blocks, 8/CU
    shapelet_mfma_kernel<<<grid, dim3(NTH), 0, stream>>>(x, shp, pen, ss_ws, out);
}

// Round 9
// 113.857 us; speedup vs baseline: 1.0114x; 1.0114x over previous
//
#include <hip/hip_runtime.h>
#include <hip/hip_fp16.h>
#include <hip/hip_bf16.h>

// B=64, M=16, T=2048, L=64, K=32, N=1985
#define B_ 64
#define M_ 16
#define T_ 2048
#define L_ 64
#define K_ 32
#define N_ (T_ - L_ + 1)   // 1985
#define NP 1988            // padded pen row (mult of 4 -> 8B-aligned ushort4 loads)
#define TN 32              // n-positions per block
#define NB 2               // b's per block; waves: w = 2*bi + nsub
#define NTH 256
#define XROW 96            // xbuf row elems (95 used = 32 + 63), 12 uint4 groups
#define STSTR 72           // st row stride elems (64+8)
#define SQSTR 36           // sqw row stride (32+4)

typedef __attribute__((ext_vector_type(8))) short bf16x8;
typedef __attribute__((ext_vector_type(4))) float f32x4;

__device__ __forceinline__ unsigned short f2bf(float f) {
    __hip_bfloat16 h = __float2bfloat16(f);
    return __builtin_bit_cast(unsigned short, h);
}
__device__ __forceinline__ float h2f(unsigned short u) {
    return __half2float(__builtin_bit_cast(__half, u));
}

// funnel: low 32 of ((hi:lo) >> sh), sh in {0,16} -> v_alignbit_b32
__device__ __forceinline__ unsigned funnel16(unsigned lo, unsigned hi, unsigned sh) {
    return (unsigned)(((((unsigned long long)hi) << 32) | lo) >> sh);
}

// Extract 16B at byte offset 2*rho from the 32B window {a,b} (aligned b128 pair).
__device__ __forceinline__ bf16x8 extract_frag(uint4 a, uint4 b, unsigned sh, int c2) {
    unsigned t0 = funnel16(a.x, a.y, sh), t1 = funnel16(a.y, a.z, sh);
    unsigned t2 = funnel16(a.z, a.w, sh), t3 = funnel16(a.w, b.x, sh);
    unsigned t4 = funnel16(b.x, b.y, sh), t5 = funnel16(b.y, b.z, sh);
    unsigned t6 = funnel16(b.z, b.w, sh);
    const bool s2 = (c2 & 2), s1 = (c2 & 1);
    unsigned u0 = s2 ? t2 : t0, u1 = s2 ? t3 : t1, u2 = s2 ? t4 : t2;
    unsigned u3 = s2 ? t5 : t3, u4 = s2 ? t6 : t4;
    union { unsigned u[4]; bf16x8 v; } cvt;
    cvt.u[0] = s1 ? u1 : u0; cvt.u[1] = s1 ? u2 : u1;
    cvt.u[2] = s1 ? u3 : u2; cvt.u[3] = s1 ? u4 : u3;
    return cvt.v;
}

// penh[r][n'] = fp16( elu(-pmap[r][min(n',N-1)]) + 2 ), r over K*M, n' over NP.
// ss[k] = sum_l shp[k][l]^2 (fp32). out[] = +inf.
__global__ void pen_init_kernel(const float* __restrict__ pmap,
                                const float* __restrict__ shp,
                                unsigned short* __restrict__ penh,
                                float* __restrict__ ss_ws,
                                unsigned* __restrict__ out) {
    const int gid = blockIdx.x * 256 + threadIdx.x;
    if (gid < B_ * K_) out[gid] = 0x7F800000u;  // +inf
    if (gid < K_) {
        float s = 0.f;
        for (int l = 0; l < L_; ++l) { float v = shp[gid * L_ + l]; s = fmaf(v, v, s); }
        ss_ws[gid] = s;
    }
    const int RQ = NP / 4;  // 497 quads per row
    if (gid < K_ * M_ * RQ) {
        const int r = gid / RQ;
        const int q4 = (gid - r * RQ) * 4;
        const float* src = pmap + (size_t)r * N_;
        ushort4 o;
        unsigned short* po = (unsigned short*)&o;
#pragma unroll
        for (int i = 0; i < 4; ++i) {
            int n = q4 + i; if (n >= N_) n = N_ - 1;
            const float p = src[n];
            const float pe = (p < 0.f) ? (2.f - p) : (__expf(-p) + 1.f);
            po[i] = __builtin_bit_cast(unsigned short, __float2half(pe));
        }
        *(ushort4*)(penh + (size_t)r * NP + q4) = o;
    }
}

__global__ __launch_bounds__(NTH, 2)
void shapelet_mfma_kernel(const float* __restrict__ x,
                          const float* __restrict__ shp,
                          const unsigned short* __restrict__ penh,
                          const float* __restrict__ ss_ws,
                          unsigned* __restrict__ out) {
    // LDS: 6144 + 4608 + 4608 = 15.4 KB -> 8 blocks/CU
    __shared__ __align__(16) unsigned short xbuf[NB][M_][XROW];  // x as bf16 bits
    __shared__ __align__(16) unsigned short st[K_][STSTR];       // shapelets bf16
    __shared__ __align__(16) float sqw[NB][M_][SQSTR];           // fp32 sliding sum x^2

    const int tid = threadIdx.x;
    const int n0 = blockIdx.x * TN;
    const int b0 = blockIdx.y * NB;
    const bool fast = (n0 + XROW <= T_);   // false only for last tile (n0=1984)

    // ---- stage x[b0+bi][m][n0..n0+94] as bf16: 2*16*24 float4-groups ----
    for (int g = tid; g < NB * M_ * 24; g += NTH) {
        const int bi = g / 384, rem = g - bi * 384;
        const int m = rem / 24, j4 = (rem - m * 24) * 4;
        const float* src = x + ((size_t)(b0 + bi) * M_ + m) * T_ + n0 + j4;
        float4 v;
        if (fast) {
            v = *(const float4*)src;
        } else {
            v = make_float4(0.f, 0.f, 0.f, 0.f);
            const int t = n0 + j4;
            if (t     < T_) v.x = src[0];
            if (t + 1 < T_) v.y = src[1];
            if (t + 2 < T_) v.z = src[2];
            if (t + 3 < T_) v.w = src[3];
        }
        ushort4 sv = { f2bf(v.x), f2bf(v.y), f2bf(v.z), f2bf(v.w) };
        *(ushort4*)&xbuf[bi][m][j4] = sv;
    }
    // ---- stage shapelets st[k][l] bf16 ----
    for (int i = tid; i < K_ * 16; i += NTH) {
        const int k = i >> 4, l4 = (i & 15) * 4;
        float4 v = *(const float4*)(shp + k * L_ + l4);
        ushort4 sv = { f2bf(v.x), f2bf(v.y), f2bf(v.z), f2bf(v.w) };
        *(ushort4*)&st[k][l4] = sv;
    }
    // ---- sqw fp32 sliding window: threads 0..127 -> (bi, m, 8-n chunk) ----
    if (tid < NB * M_ * 4) {
        const int bi = tid >> 6, m = (tid >> 2) & 15, j0 = (tid & 3) * 8;
        const float* xr = x + ((size_t)(b0 + bi) * M_ + m) * T_ + n0;
        float s = 0.f;
        if (fast) {
#pragma unroll
            for (int qd = 0; qd < 16; ++qd) {
                float4 v = *(const float4*)(xr + j0 + qd * 4);
                s = fmaf(v.x, v.x, s); s = fmaf(v.y, v.y, s);
                s = fmaf(v.z, v.z, s); s = fmaf(v.w, v.w, s);
            }
            sqw[bi][m][j0] = s;
#pragma unroll
            for (int d = 1; d < 8; ++d) {
                float a = xr[j0 + d + L_ - 1], r = xr[j0 + d - 1];
                s += a * a - r * r;
                sqw[bi][m][j0 + d] = s;
            }
        } else {
            for (int l = 0; l < L_; ++l) {
                float v = (n0 + j0 + l < T_) ? xr[j0 + l] : 0.f;
                s = fmaf(v, v, s);
            }
            sqw[bi][m][j0] = s;
            for (int d = 1; d < 8; ++d) {
                float a = (n0 + j0 + d + L_ - 1 < T_) ? xr[j0 + d + L_ - 1] : 0.f;
                float r = (n0 + j0 + d - 1 < T_) ? xr[j0 + d - 1] : 0.f;
                s += a * a - r * r;
                sqw[bi][m][j0 + d] = s;
            }
        }
    }
    __syncthreads();

    // ---- per-lane MFMA coordinates: wave w = 2*bi + nsub ----
    const int lane = tid & 63;
    const int w    = tid >> 6;
    const int bi   = w >> 1;
    const int nsub = w & 1;
    const int rl = lane & 15;      // A-row (n within 16-subtile) / B-col (k)
    const int q  = lane >> 4;      // quad
    const int rho = rl & 7, r8 = rl >> 3;
    const unsigned sh = (unsigned)((rho & 1) * 16);
    const int c2 = rho >> 1;
    const int Gb = 2 * nsub + q + r8;       // 16B-group base for A windows
    const int nrow = n0 + 16 * nsub + 4 * q; // lane's 4 output rows: nrow + reg

    // b_frags (registers, whole kernel): st[16t+rl][8q+32h .. +7]
    bf16x8 bfr[2][2];
#pragma unroll
    for (int t = 0; t < 2; ++t)
#pragma unroll
        for (int h = 0; h < 2; ++h)
            bfr[t][h] = *(const bf16x8*)&st[16 * t + rl][8 * q + 32 * h];

    const float ssk0 = ss_ws[rl], ssk1 = ss_ws[16 + rl];

    const unsigned short* ph0 = penh + (size_t)rl * (M_ * NP) + nrow;        // k=rl
    const unsigned short* ph1 = ph0 + (size_t)16 * M_ * NP;                  // k=rl+16

    f32x4 wd0 = (f32x4)0.f, wd1 = (f32x4)0.f;
    const f32x4 zero = (f32x4)0.f;

#pragma unroll 2
    for (int m = 0; m < M_; ++m) {
        // ---- pen (fp16) for this m: 8B per k-half, aligned (NP mult 4) ----
        float pe0[4], pe1[4];
        if (fast) {
            ushort4 h0 = *(const ushort4*)(ph0 + (size_t)m * NP);
            ushort4 h1 = *(const ushort4*)(ph1 + (size_t)m * NP);
            pe0[0] = h2f(h0.x); pe0[1] = h2f(h0.y); pe0[2] = h2f(h0.z); pe0[3] = h2f(h0.w);
            pe1[0] = h2f(h1.x); pe1[1] = h2f(h1.y); pe1[2] = h2f(h1.z); pe1[3] = h2f(h1.w);
        } else {
            const unsigned short* r0_ = ph0 + (size_t)m * NP;
            const unsigned short* r1_ = ph1 + (size_t)m * NP;
#pragma unroll
            for (int i = 0; i < 4; ++i) {
                const bool valid = (nrow + i) < N_;
                pe0[i] = valid ? h2f(r0_[i]) : 2.f;
                pe1[i] = valid ? h2f(r1_[i]) : 2.f;
            }
        }

        const uint4* px = (const uint4*)&xbuf[bi][m][0];
        uint4 w0_ = px[Gb],     w1_ = px[Gb + 1];  // h=0 window
        uint4 w2_ = px[Gb + 4], w3_ = px[Gb + 5];  // h=1 window
        bf16x8 a0 = extract_frag(w0_, w1_, sh, c2);
        bf16x8 a1 = extract_frag(w2_, w3_, sh, c2);

        f32x4 c0_ = __builtin_amdgcn_mfma_f32_16x16x32_bf16(a0, bfr[0][0], zero, 0, 0, 0);
        c0_       = __builtin_amdgcn_mfma_f32_16x16x32_bf16(a1, bfr[0][1], c0_, 0, 0, 0);
        f32x4 c1_ = __builtin_amdgcn_mfma_f32_16x16x32_bf16(a0, bfr[1][0], zero, 0, 0, 0);
        c1_       = __builtin_amdgcn_mfma_f32_16x16x32_bf16(a1, bfr[1][1], c1_, 0, 0, 0);

        f32x4 sq = *(const f32x4*)&sqw[bi][m][16 * nsub + 4 * q];
#pragma unroll
        for (int r = 0; r < 4; ++r) {
            float t0v = fmaf(-2.f, c0_[r], sq[r] + ssk0);
            wd0[r] = fmaf(pe0[r], t0v, wd0[r]);
            float t1v = fmaf(-2.f, c1_[r], sq[r] + ssk1);
            wd1[r] = fmaf(pe1[r], t1v, wd1[r]);
        }
    }

    // ---- min over lane's 4 rows -> across quads -> atomicMin per (b0+bi, k) ----
#pragma unroll
    for (int t = 0; t < 2; ++t) {
        float lmin = __int_as_float(0x7F800000);
        const f32x4& wdv = t ? wd1 : wd0;
#pragma unroll
        for (int r = 0; r < 4; ++r) {
            if (nrow + r < N_) lmin = fminf(lmin, wdv[r]);
        }
        lmin = fminf(lmin, __shfl_xor(lmin, 16));
        lmin = fminf(lmin, __shfl_xor(lmin, 32));
        if (q == 0) {
            atomicMin(out + (size_t)(b0 + bi) * K_ + 16 * t + rl,
                      __float_as_uint(fmaxf(lmin, 0.f)));
        }
    }
}

extern "C" void kernel_launch(void* const* d_in, const int* in_sizes, int n_in,
                              void* d_out, int out_size, void* d_ws, size_t ws_size,
                              hipStream_t stream) {
    const float* x    = (const float*)d_in[0];   // (B, M, T)
    const float* shp  = (const float*)d_in[1];   // (K, L)
    const float* pmap = (const float*)d_in[2];   // (K, M, N)
    unsigned* out = (unsigned*)d_out;            // (B, K) float bits
    unsigned short* penh = (unsigned short*)d_ws;        // (K*M, NP) fp16, ~2.04 MB
    float* ss_ws = (float*)(penh + (size_t)K_ * M_ * NP);

    const int work = K_ * M_ * (NP / 4);         // 254,464
    pen_init_kernel<<<dim3((work + 255) / 256), dim3(256), 0, stream>>>(
        pmap, shp, penh, ss_ws, out);

    dim3 grid((N_ + TN - 1) / TN, B_ / NB);      // 63 x 32 = 2016 blocks, ~8/CU
    shapelet_mfma_kernel<<<grid, dim3(NTH), 0, stream>>>(x, shp, penh, ss_ws, out);
}

// Round 11
// 100.947 us; speedup vs baseline: 1.1407x; 1.1279x over previous
//
#include <hip/hip_runtime.h>
#include <hip/hip_bf16.h>

// B=64, M=16, T=2048, L=64, K=32, N=1985
#define B_ 64
#define M_ 16
#define T_ 2048
#define L_ 64
#define K_ 32
#define N_ (T_ - L_ + 1)   // 1985
#define KMN (K_ * M_ * N_) // 1,016,320 (= 4 * 254,080 exactly)
#define TN 64              // n-positions per block
#define NTH 256            // 4 waves: wave w owns n-subtile [16w,16w+16), both k-tiles
#define XROW 144           // per-plane row elems; need j<=123 (e0max=84, +32+7).
                           // 144 elems = 72 dw == 8 (mod 32) -> planes at bank
                           // offsets {0,8,16,24}: exhaustive lane count gives a
                           // UNIFORM 4 touches/bank = the 512B/wave floor.
#define STSTR 72           // st row stride elems (16B-aligned b128 reads)
#define SQSTR 64           // sqw row stride (reads are q-only broadcasts)

typedef __attribute__((ext_vector_type(8))) short bf16x8;
typedef __attribute__((ext_vector_type(4))) float f32x4;

__device__ __forceinline__ unsigned short f2bf(float f) {
    __hip_bfloat16 h = __float2bfloat16(f);
    return __builtin_bit_cast(unsigned short, h);
}

// pen[i] = elu(-pmap[i]) + 2 (flat over K*M*N); ss[k] = sum_l shp[k][l]^2 (fp32);
// out[] initialized to +inf.
__global__ void pen_init_kernel(const float* __restrict__ pmap,
                                const float* __restrict__ shp,
                                float* __restrict__ pen,
                                float* __restrict__ ss_ws,
                                unsigned* __restrict__ out) {
    const int gid = blockIdx.x * 256 + threadIdx.x;
    if (gid < B_ * K_) out[gid] = 0x7F800000u;  // +inf
    if (gid < K_) {
        float s = 0.f;
        for (int l = 0; l < L_; ++l) { float v = shp[gid * L_ + l]; s = fmaf(v, v, s); }
        ss_ws[gid] = s;
    }
    if (gid < KMN / 4) {
        const int i4 = gid * 4;
        float4 p = *(const float4*)(pmap + i4);
        float4 r;
        r.x = (p.x < 0.f) ? (2.f - p.x) : (__expf(-p.x) + 1.f);
        r.y = (p.y < 0.f) ? (2.f - p.y) : (__expf(-p.y) + 1.f);
        r.z = (p.z < 0.f) ? (2.f - p.z) : (__expf(-p.z) + 1.f);
        r.w = (p.w < 0.f) ? (2.f - p.w) : (__expf(-p.w) + 1.f);
        *(float4*)(pen + i4) = r;
    }
}

__global__ __launch_bounds__(NTH, 2)
void shapelet_mfma_kernel(const float* __restrict__ x,
                          const float* __restrict__ shp,
                          const float* __restrict__ pen,
                          const float* __restrict__ ss_ws,
                          unsigned* __restrict__ out) {
    // LDS: 18432 + 4608 + 4096 = 27136 B -> 6 blocks/CU (27136*6 <= 160 KiB)
    // xbuf4[m][s][j] = bf16(x[b][m][n0 + j + s]) : 4 shifted planes so every
    // A-fragment (elem start o = 16w+8q+rl+32h, o%4 == rl%4) is one
    // ds_read2_b64 from plane s=rl&3 at 4-aligned e = o - s. Zero extract VALU.
    __shared__ __align__(16) unsigned short xbuf4[M_][4][XROW];
    __shared__ __align__(16) unsigned short st[K_][STSTR];   // shapelets bf16
    __shared__ __align__(16) float sqw[M_][SQSTR];           // fp32 sliding sum x^2

    const int tid = threadIdx.x;
    const int n0 = blockIdx.x * TN;
    const int b  = blockIdx.y;
    const bool fast = (n0 + 128 <= T_);   // false only for last tile (n0=1984)

    // ---- stage x as 4 shifted bf16 planes: j4 = 0..120 -> j coverage 0..123 ----
    const float* xb = x + ((size_t)b * M_) * T_ + n0;
    for (int g = tid; g < M_ * 31; g += NTH) {
        const int m = g / 31, j4 = (g - m * 31) * 4;     // j4 in {0,4,...,120}
        const float* src = xb + m * T_ + j4;
        float h[8];
        if (fast) {
            float4 v0 = *(const float4*)src;
            float4 v1 = *(const float4*)(src + 4);
            h[0] = v0.x; h[1] = v0.y; h[2] = v0.z; h[3] = v0.w;
            h[4] = v1.x; h[5] = v1.y; h[6] = v1.z; h[7] = v1.w;
        } else {
#pragma unroll
            for (int i = 0; i < 8; ++i)
                h[i] = (n0 + j4 + i < T_) ? src[i] : 0.f;
        }
        unsigned short hb[8];
#pragma unroll
        for (int i = 0; i < 8; ++i) hb[i] = f2bf(h[i]);
#pragma unroll
        for (int s = 0; s < 4; ++s) {
            ushort4 sv = { hb[s], hb[s + 1], hb[s + 2], hb[s + 3] };
            *(ushort4*)&xbuf4[m][s][j4] = sv;
        }
    }
    // ---- stage shapelets st[k][l] bf16 ----
    for (int i = tid; i < K_ * 16; i += NTH) {
        const int k = i >> 4, l4 = (i & 15) * 4;
        float4 v = *(const float4*)(shp + k * L_ + l4);
        ushort4 sv = { f2bf(v.x), f2bf(v.y), f2bf(v.z), f2bf(v.w) };
        *(ushort4*)&st[k][l4] = sv;
    }
    // ---- sqw fp32 sliding window: 8 threads per m, 8 n each (threads 0..127) ----
    if (tid < M_ * 8) {
        const int m = tid >> 3, j0 = (tid & 7) * 8;
        const float* xr = x + ((size_t)b * M_ + m) * T_ + n0;
        float s = 0.f;
        if (fast) {
#pragma unroll
            for (int qd = 0; qd < 16; ++qd) {
                float4 v = *(const float4*)(xr + j0 + qd * 4);
                s = fmaf(v.x, v.x, s); s = fmaf(v.y, v.y, s);
                s = fmaf(v.z, v.z, s); s = fmaf(v.w, v.w, s);
            }
            sqw[m][j0] = s;
#pragma unroll
            for (int d = 1; d < 8; ++d) {
                float a = xr[j0 + d + L_ - 1], r = xr[j0 + d - 1];
                s += a * a - r * r;
                sqw[m][j0 + d] = s;
            }
        } else {
            for (int l = 0; l < L_; ++l) {
                float v = (n0 + j0 + l < T_) ? xr[j0 + l] : 0.f;
                s = fmaf(v, v, s);
            }
            sqw[m][j0] = s;
            for (int d = 1; d < 8; ++d) {
                float a = (n0 + j0 + d + L_ - 1 < T_) ? xr[j0 + d + L_ - 1] : 0.f;
                float r = (n0 + j0 + d - 1 < T_) ? xr[j0 + d - 1] : 0.f;
                s += a * a - r * r;
                sqw[m][j0 + d] = s;
            }
        }
    }
    __syncthreads();

    // ---- per-lane MFMA coordinates ----
    const int lane = tid & 63;
    const int w  = tid >> 6;       // wave -> n-subtile [16w, 16w+16)
    const int rl = lane & 15;      // A-row (n within subtile) / B-col (k within tile)
    const int q  = lane >> 4;      // quad
    const int sp = rl & 3;                          // shift plane
    const int e0 = 16 * w + 8 * q + (rl & ~3);      // 4-aligned elem base (max 84)
    const int eq = e0 >> 2;                         // uint2 index (max 21; +9 <= 30 < 36)
    const int nrow = n0 + 16 * w + 4 * q;           // lane's 4 output rows: nrow + reg

    // b_frags (registers, whole kernel): st[16t+rl][8q+32h .. +7]
    bf16x8 bfr[2][2];
#pragma unroll
    for (int t = 0; t < 2; ++t)
#pragma unroll
        for (int h = 0; h < 2; ++h)
            bfr[t][h] = *(const bf16x8*)&st[16 * t + rl][8 * q + 32 * h];

    const float ssk0 = ss_ws[rl], ssk1 = ss_ws[16 + rl];

    const float* pr0 = pen + (size_t)rl * (M_ * N_) + nrow;         // k = rl
    const float* pr1 = pr0 + (size_t)16 * M_ * N_;                  // k = rl+16

    f32x4 wd0 = (f32x4)0.f, wd1 = (f32x4)0.f;
    const f32x4 zero = (f32x4)0.f;

#pragma unroll 2
    for (int m = 0; m < M_; ++m) {
        // ---- pen fp32 for this m ----
        float4 p0, p1;
        if (fast) {
            p0 = *(const float4*)(pr0 + (size_t)m * N_);
            p1 = *(const float4*)(pr1 + (size_t)m * N_);
        } else {
            p0 = make_float4(2.f, 2.f, 2.f, 2.f);   // masked at the min
            p1 = make_float4(2.f, 2.f, 2.f, 2.f);
            const float* r0_ = pr0 + (size_t)m * N_;
            const float* r1_ = pr1 + (size_t)m * N_;
            if (nrow     < N_) { p0.x = r0_[0]; p1.x = r1_[0]; }
            if (nrow + 1 < N_) { p0.y = r0_[1]; p1.y = r1_[1]; }
            if (nrow + 2 < N_) { p0.z = r0_[2]; p1.z = r1_[2]; }
            if (nrow + 3 < N_) { p0.w = r0_[3]; p1.w = r1_[3]; }
        }

        // ---- A-frags: 8B-aligned LDS read pairs, no extract VALU ----
        const uint2* prow = (const uint2*)&xbuf4[m][sp][0];  // row 16B-aligned
        uint2 lo0 = prow[eq],     hi0 = prow[eq + 1];        // frag h=0
        uint2 lo1 = prow[eq + 8], hi1 = prow[eq + 9];        // frag h=1 (+32 elem)
        union { uint2 u2[2]; bf16x8 v; } fa0, fa1;
        fa0.u2[0] = lo0; fa0.u2[1] = hi0;
        fa1.u2[0] = lo1; fa1.u2[1] = hi1;

        f32x4 c0_ = __builtin_amdgcn_mfma_f32_16x16x32_bf16(fa0.v, bfr[0][0], zero, 0, 0, 0);
        c0_       = __builtin_amdgcn_mfma_f32_16x16x32_bf16(fa1.v, bfr[0][1], c0_, 0, 0, 0);
        f32x4 c1_ = __builtin_amdgcn_mfma_f32_16x16x32_bf16(fa0.v, bfr[1][0], zero, 0, 0, 0);
        c1_       = __builtin_amdgcn_mfma_f32_16x16x32_bf16(fa1.v, bfr[1][1], c1_, 0, 0, 0);

        f32x4 sq = *(const f32x4*)&sqw[m][16 * w + 4 * q];
        const float pe0[4] = { p0.x, p0.y, p0.z, p0.w };
        const float pe1[4] = { p1.x, p1.y, p1.z, p1.w };
#pragma unroll
        for (int r = 0; r < 4; ++r) {
            float t0v = fmaf(-2.f, c0_[r], sq[r] + ssk0);
            wd0[r] = fmaf(pe0[r], t0v, wd0[r]);
            float t1v = fmaf(-2.f, c1_[r], sq[r] + ssk1);
            wd1[r] = fmaf(pe1[r], t1v, wd1[r]);
        }
    }

    // ---- min over lane's 4 rows -> across quads -> atomicMin per (b,k) ----
#pragma unroll
    for (int t = 0; t < 2; ++t) {
        float lmin = __int_as_float(0x7F800000);
        const f32x4& wdv = t ? wd1 : wd0;
#pragma unroll
        for (int r = 0; r < 4; ++r) {
            if (nrow + r < N_) lmin = fminf(lmin, wdv[r]);
        }
        lmin = fminf(lmin, __shfl_xor(lmin, 16));
        lmin = fminf(lmin, __shfl_xor(lmin, 32));
        if (q == 0) {
            atomicMin(out + (size_t)b * K_ + 16 * t + rl,
                      __float_as_uint(fmaxf(lmin, 0.f)));
        }
    }
}

extern "C" void kernel_launch(void* const* d_in, const int* in_sizes, int n_in,
                              void* d_out, int out_size, void* d_ws, size_t ws_size,
                              hipStream_t stream) {
    const float* x    = (const float*)d_in[0];   // (B, M, T)
    const float* shp  = (const float*)d_in[1];   // (K, L)
    const float* pmap = (const float*)d_in[2];   // (K, M, N)
    unsigned* out = (unsigned*)d_out;            // (B, K) float bits
    float* pen   = (float*)d_ws;                 // (K, M, N) elu(-pmap)+2, 3.9 MB
    float* ss_ws = pen + KMN;                    // (K,) fp32 sum s^2

    pen_init_kernel<<<dim3((KMN / 4 + 255) / 256), dim3(256), 0, stream>>>(
        pmap, shp, pen, ss_ws, out);

    dim3 grid((N_ + TN - 1) / TN, B_);           // 32 x 64 = 2048 blocks
    shapelet_mfma_kernel<<<grid, dim3(NTH), 0, stream>>>(x, shp, pen, ss_ws, out);
}